// Round 5
// baseline (520.219 us; speedup 1.0000x reference)
//
#include <hip/hip_runtime.h>
#include <math.h>

#define Bdim 2
#define Nn   2048
#define Kn   30
#define KP   32                   // padded edges per node
#define DNc  256
#define DEc  128
#define NODES (Bdim*Nn)           // 4096
#define EDGES (Bdim*Nn*Kn)        // 122880
#define RPAD  (NODES*KP)          // 131072 padded edge rows
#define EPSF 1e-6f

#define BK 64
#define LDA (BK+8)    // padded GEMM LDS row (bf16 elems)
#define LDA0 40       // padded K=32 GEMM LDS row
#define LDP 136       // LDS tile row stride (shorts), 16B-aligned rows

typedef __attribute__((ext_vector_type(8))) short short8;
typedef __attribute__((ext_vector_type(4))) short sh4;
typedef __attribute__((ext_vector_type(4))) float floatx4;

__device__ __forceinline__ float softplusf(float x){
    float e = __expf(-fabsf(x));
    return fmaxf(x, 0.f) + __logf(1.f + e);
}

__device__ __forceinline__ unsigned short f2bf(float x){
    union { float f; unsigned u; } v; v.f = x;
    unsigned r = v.u + 0x7fff + ((v.u >> 16) & 1);   // RNE
    return (unsigned short)(r >> 16);
}
__device__ __forceinline__ float bf2f(unsigned short h){
    union { unsigned u; float f; } v; v.u = ((unsigned)h) << 16;
    return v.f;
}

// ---------------- K1: per-node geometry ----------------
__global__ __launch_bounds__(256) void k_geom(
    const float* __restrict__ X, const int* __restrict__ C,
    float* __restrict__ Xc, float* __restrict__ Rm,
    float* __restrict__ feat, float* __restrict__ mask_out)
{
    int id = blockIdx.x*256 + threadIdx.x;
    if (id >= NODES) return;
    float a[4][3];
    #pragma unroll
    for (int t=0;t<4;++t)
        #pragma unroll
        for (int d=0;d<3;++d) a[t][d] = X[id*12 + t*3 + d];
    #pragma unroll
    for (int d=0; d<3; ++d){
        float s = __fadd_rn(__fadd_rn(__fadd_rn(a[0][d],a[1][d]),a[2][d]),a[3][d]);
        Xc[id*3+d] = __fmul_rn(s, 0.25f);
    }
    mask_out[id] = (C[id] > 0) ? 1.f : 0.f;

    float u[3], v[3], w[3], b2[3], v0[3], vv[3];
    #pragma unroll
    for (int d=0;d<3;++d) b2[d] = a[2][d]-a[1][d];
    float n2 = sqrtf(b2[0]*b2[0]+b2[1]*b2[1]+b2[2]*b2[2]);
    #pragma unroll
    for (int d=0;d<3;++d) u[d] = b2[d]/(n2+EPSF);
    #pragma unroll
    for (int d=0;d<3;++d) v0[d] = a[0][d]-a[1][d];
    float dt = v0[0]*u[0]+v0[1]*u[1]+v0[2]*u[2];
    #pragma unroll
    for (int d=0;d<3;++d) vv[d] = v0[d] - dt*u[d];
    float nv = sqrtf(vv[0]*vv[0]+vv[1]*vv[1]+vv[2]*vv[2]);
    #pragma unroll
    for (int d=0;d<3;++d) v[d] = vv[d]/(nv+EPSF);
    w[0] = u[1]*v[2]-u[2]*v[1];
    w[1] = u[2]*v[0]-u[0]*v[2];
    w[2] = u[0]*v[1]-u[1]*v[0];
    #pragma unroll
    for (int d=0;d<3;++d){
        Rm[id*9 + d*3 + 0] = u[d];
        Rm[id*9 + d*3 + 1] = v[d];
        Rm[id*9 + d*3 + 2] = w[d];
    }
    float bonds[3][3];
    #pragma unroll
    for (int d=0;d<3;++d){
        bonds[0][d] = a[1][d]-a[0][d];
        bonds[1][d] = b2[d];
        bonds[2][d] = a[3][d]-a[2][d];
    }
    #pragma unroll
    for (int bi=0;bi<3;++bi){
        float nb = sqrtf(bonds[bi][0]*bonds[bi][0]+bonds[bi][1]*bonds[bi][1]+bonds[bi][2]*bonds[bi][2]);
        #pragma unroll
        for (int d=0;d<3;++d) feat[id*12 + bi*4 + d] = bonds[bi][d]/(nb+EPSF);
        feat[id*12 + bi*4 + 3] = logf(nb+EPSF);
    }
}

// ---------------- K1b: node_h init (f32 + bf16) ----------------
__global__ __launch_bounds__(256) void k_nodeh(
    const float* __restrict__ feat, const float* __restrict__ Wn,
    const float* __restrict__ bn, const int* __restrict__ C,
    float* __restrict__ node_h, unsigned short* __restrict__ node_bf)
{
    int nid = blockIdx.x;
    int c   = threadIdx.x;
    __shared__ float f[12];
    if (c < 12) f[c] = feat[nid*12 + c];
    __syncthreads();
    float acc = bn[c];
    #pragma unroll
    for (int k=0;k<12;++k) acc += f[k]*Wn[k*DNc + c];
    float mask = (C[nid] > 0) ? 1.f : 0.f;
    float r = acc*mask;
    node_h[nid*DNc + c] = r;
    node_bf[nid*DNc + c] = f2bf(r);
}

// ---------------- K2: kNN top-30, wave-per-node, register selection ----------------
__global__ __launch_bounds__(256) void k_knn(
    const float* __restrict__ Xc, const int* __restrict__ C,
    int* __restrict__ eidx, float* __restrict__ eidx_f)
{
    __shared__ float sx[Nn], sy[Nn], sz[Nn], sadd[Nn];
    int tid  = threadIdx.x;
    int lane = tid & 63, wave = tid >> 6;
    int node0 = blockIdx.x*4;            // 4 nodes per block, same batch
    int base  = (node0 >> 11) << 11;     // batch base node
    for (int j=tid; j<Nn; j+=256){
        int gj = base + j;
        sx[j] = Xc[gj*3+0]; sy[j] = Xc[gj*3+1]; sz[j] = Xc[gj*3+2];
        sadd[j] = (C[gj] > 0) ? 0.f : 1e9f;
    }
    __syncthreads();

    int node = node0 + wave;
    int iloc = node & (Nn-1);
    float xi = sx[iloc], yi = sy[iloc], zi = sz[iloc];

    unsigned long long kreg[32];
    unsigned long long gm[8];
    #pragma unroll
    for (int t=0; t<32; ++t){
        int j = lane + t*64;
        float dx = __fsub_rn(xi, sx[j]);
        float dy = __fsub_rn(yi, sy[j]);
        float dz = __fsub_rn(zi, sz[j]);
        float vv = __fadd_rn(__fadd_rn(__fmul_rn(dx,dx),__fmul_rn(dy,dy)),__fmul_rn(dz,dz));
        vv = __fadd_rn(vv, sadd[j]);
        if (j == iloc) vv = __fadd_rn(vv, 1e9f);
        union { float f; unsigned u; } cv; cv.f = vv;
        kreg[t] = (((unsigned long long)cv.u) << 11) | (unsigned)j;
    }
    #pragma unroll
    for (int g=0; g<8; ++g){
        unsigned long long a = kreg[4*g+0], b = kreg[4*g+1];
        unsigned long long c = kreg[4*g+2], d = kreg[4*g+3];
        unsigned long long m1 = a<b?a:b, m2 = c<d?c:d;
        gm[g] = m1<m2?m1:m2;
    }
    unsigned long long m = gm[0]; int marg = 0;
    #pragma unroll
    for (int g=1; g<8; ++g) if (gm[g] < m){ m = gm[g]; marg = g; }

    for (int kk=0; kk<Kn; ++kk){
        unsigned long long best = m;
        #pragma unroll
        for (int d=1; d<64; d<<=1){
            unsigned long long o = __shfl_xor(best, d, 64);
            if (o < best) best = o;
        }
        if (lane == 0){
            int j = (int)(best & 2047ull);
            eidx  [(size_t)node*Kn + kk] = j;
            eidx_f[(size_t)node*Kn + kk] = (float)j;
        }
        if (m == best){
            #pragma unroll
            for (int g=0; g<8; ++g){
                if (marg == g){
                    #pragma unroll
                    for (int t=0; t<4; ++t)
                        if (kreg[4*g+t] == best) kreg[4*g+t] = ~0ull;
                    unsigned long long a = kreg[4*g+0], b = kreg[4*g+1];
                    unsigned long long c = kreg[4*g+2], d = kreg[4*g+3];
                    unsigned long long m1 = a<b?a:b, m2 = c<d?c:d;
                    gm[g] = m1<m2?m1:m2;
                }
            }
            m = gm[0]; marg = 0;
            #pragma unroll
            for (int g=1; g<8; ++g) if (gm[g] < m){ m = gm[g]; marg = g; }
        }
    }
}

// ---------------- K3a: edge features, one thread per padded edge slot ----------------
__global__ __launch_bounds__(256) void k_edge_feat(
    const float* __restrict__ Xc, const float* __restrict__ Rm,
    const int* __restrict__ eidx, const int* __restrict__ C,
    unsigned short* __restrict__ featp,
    float* __restrict__ mask_ij_out, float* __restrict__ mask_pad,
    int* __restrict__ jg_pad, float* __restrict__ cnt)
{
    int r   = blockIdx.x*256 + threadIdx.x;      // padded edge row
    int nid = r >> 5;
    int k   = r & 31;
    int b   = nid >> 11;
    float mij = 0.f;
    int   jb  = nid;
    float f[28];
    if (k < Kn){
        int e = nid*Kn + k;
        int j = eidx[e];
        jb = (b<<11) + j;
        mij = (C[nid] > 0 && C[jb] > 0) ? 1.f : 0.f;
        mask_ij_out[e] = mij;
        float xi0 = Xc[nid*3+0], xi1 = Xc[nid*3+1], xi2 = Xc[nid*3+2];
        float d0  = Xc[jb*3+0]-xi0;
        float d1  = Xc[jb*3+1]-xi1;
        float d2v = Xc[jb*3+2]-xi2;
        float dist = sqrtf(d0*d0 + d1*d1 + d2v*d2v);
        float ri[9], rj[9];
        #pragma unroll
        for (int q=0;q<9;++q) ri[q] = Rm[nid*9+q];
        #pragma unroll
        for (int q=0;q<9;++q) rj[q] = Rm[jb*9+q];
        #pragma unroll
        for (int c=0; c<16; ++c){
            float ctr = (20.f/15.f)*(float)c;
            float t = (dist - ctr)*(1.f/1.25f);
            f[c] = expf(-t*t);
        }
        #pragma unroll
        for (int cc=0; cc<3; ++cc){
            float loc = ri[0*3+cc]*d0 + ri[1*3+cc]*d1 + ri[2*3+cc]*d2v;
            f[16+cc] = loc/(dist+EPSF);
        }
        #pragma unroll
        for (int ee=0; ee<3; ++ee)
            #pragma unroll
            for (int ff=0; ff<3; ++ff)
                f[19+ee*3+ff] = ri[0+ee]*rj[0+ff] + ri[3+ee]*rj[3+ff] + ri[6+ee]*rj[6+ff];
    }
    jg_pad[r]   = jb;
    mask_pad[r] = mij;

    // cnt via wave ballot: one wave = exactly 2 nodes (lanes 0-31 / 32-63)
    unsigned long long bal = __ballot(mij > 0.f);
    int lane = threadIdx.x & 63;
    if (lane == 0)  cnt[r >> 5] = (float)__popcll(bal & 0xFFFFFFFFull);
    if (lane == 32) cnt[r >> 5] = (float)__popcll(bal >> 32);

    unsigned short ov[32];
    #pragma unroll
    for (int q=0;q<32;++q) ov[q] = 0;
    if (k < Kn){
        #pragma unroll
        for (int q=0;q<28;++q) ov[q] = f2bf(f[q]);
    }
    unsigned short* dst = featp + (size_t)r*32;
    #pragma unroll
    for (int q=0; q<4; ++q){
        short8 sv;
        #pragma unroll
        for (int z=0; z<8; ++z) sv[z] = (short)ov[q*8+z];
        *(short8*)(dst + q*8) = sv;
    }
}

// ---------------- K3b: E0 = featp @ We^T (K=32) + bias, *mask (swapped C-layout) ----------------
__global__ __launch_bounds__(256) void k_edge0(
    const unsigned short* __restrict__ featp, const unsigned short* __restrict__ Wp,
    const float* __restrict__ be, const float* __restrict__ mask_pad,
    unsigned short* __restrict__ edge_pad)
{
    __shared__ __align__(16) unsigned short smem[128*LDP];   // tile spans whole
    __shared__ float smask[128];
    unsigned short* Als  = smem;               // 128*LDA0 = 5120 shorts
    unsigned short* Bls  = smem + 128*LDA0;    // +5120
    unsigned short* tile = smem;

    int tid = threadIdx.x;
    int lane = tid & 63, wave = tid >> 6;
    int wm = wave >> 1, wn = wave & 1;

    // stage A (128x32) and B^T (128x32)
    {
        const unsigned short* Ab = featp + (size_t)blockIdx.x*128*32;
        #pragma unroll
        for (int it=0; it<2; ++it){
            int idx = it*256 + tid;
            int row = idx >> 2, q = idx & 3;
            *(float4*)(&Als[row*LDA0 + q*8]) = *(const float4*)(Ab + row*32 + q*8);
        }
        if (tid < 128){
            int row = tid;
            *(float4*)(&Bls[row*LDA0 + 0])  = *(const float4*)(Wp + row*32 + 0);
            *(float4*)(&Bls[row*LDA0 + 8])  = *(const float4*)(Wp + row*32 + 8);
            *(float4*)(&Bls[row*LDA0 + 16]) = *(const float4*)(Wp + row*32 + 16);
            *(float4*)(&Bls[row*LDA0 + 24]) = *(const float4*)(Wp + row*32 + 24);
        } else {
            smask[tid-128] = mask_pad[blockIdx.x*128 + (tid-128)];
        }
    }
    __syncthreads();

    floatx4 acc[4][4];
    #pragma unroll
    for (int i=0;i<4;++i)
        #pragma unroll
        for (int j=0;j<4;++j) acc[i][j] = (floatx4){0.f,0.f,0.f,0.f};
    short8 af[4], bf[4];
    int kidx = (lane>>4)*8;
    #pragma unroll
    for (int t=0;t<4;++t){
        int row = wm*64 + t*16 + (lane&15);
        af[t] = *(const short8*)(&Als[row*LDA0 + kidx]);
        int col = wn*64 + t*16 + (lane&15);
        bf[t] = *(const short8*)(&Bls[col*LDA0 + kidx]);
    }
    __syncthreads();                        // all LDS reads done before tile overwrite
    // swapped: acc[i][j]: row = wm*64+i*16+cl, col = wn*64+j*16+quad*4+rg
    #pragma unroll
    for (int i=0;i<4;++i)
        #pragma unroll
        for (int j=0;j<4;++j)
            acc[i][j] = __builtin_amdgcn_mfma_f32_16x16x32_bf16(bf[j], af[i], acc[i][j], 0,0,0);

    int quad = lane >> 4, cl = lane & 15;
    #pragma unroll
    for (int i=0;i<4;++i){
        int rowl = wm*64 + i*16 + cl;
        float mk = smask[rowl];
        #pragma unroll
        for (int j=0;j<4;++j){
            int coll = wn*64 + j*16 + quad*4;
            float4 bv = *(const float4*)&be[coll];
            sh4 w;
            w[0] = (short)f2bf((acc[i][j][0] + bv.x)*mk);
            w[1] = (short)f2bf((acc[i][j][1] + bv.y)*mk);
            w[2] = (short)f2bf((acc[i][j][2] + bv.z)*mk);
            w[3] = (short)f2bf((acc[i][j][3] + bv.w)*mk);
            *(sh4*)(&tile[rowl*LDP + coll]) = w;
        }
    }
    __syncthreads();
    {
        int rl = tid >> 1;
        int h  = tid & 1;
        unsigned short* dst = edge_pad + (size_t)(blockIdx.x*128 + rl)*128 + h*64;
        #pragma unroll
        for (int q=0; q<8; ++q)
            *(short8*)(dst + q*8) = *(const short8*)(&tile[rl*LDP + h*64 + q*8]);
    }
}

// ---------------- single fused weight-pack kernel ----------------
__global__ __launch_bounds__(256) void k_pack_all(
    const float* __restrict__ We, const float* __restrict__ Wm1,
    const float* __restrict__ Wue1, const float* __restrict__ Wue2,
    const float* __restrict__ Wm2,
    unsigned short* __restrict__ wWe0, unsigned short* __restrict__ wPQw,
    unsigned short* __restrict__ wEw, unsigned short* __restrict__ wUe2w,
    unsigned short* __restrict__ wM2w)
{
    int id = blockIdx.x*256 + threadIdx.x;
    if (id < 4096){
        int n = id >> 5, kk = id & 31;
        wWe0[id] = (kk < 28) ? f2bf(We[kk*128 + n]) : 0;
        return;
    }
    id -= 4096;
    if (id < 3*768*256){
        int l = id / (768*256);
        int rem = id % (768*256);
        int n = rem >> 8, k = rem & 255;
        int c = (n < 384) ? n : n - 384;
        int r = (n < 384) ? k : 256 + k;
        float v = (c < 256) ? Wm1[((size_t)l*640 + r)*256 + c]
                            : Wue1[((size_t)l*640 + r)*128 + (c-256)];
        wPQw[id] = f2bf(v);
        return;
    }
    id -= 3*768*256;
    if (id < 3*384*128){
        int l = id / (384*128);
        int rem = id % (384*128);
        int n = rem >> 7, k = rem & 127;
        int r = 512 + k;
        float v = (n < 256) ? Wm1[((size_t)l*640 + r)*256 + n]
                            : Wue1[((size_t)l*640 + r)*128 + (n-256)];
        wEw[id] = f2bf(v);
        return;
    }
    id -= 3*384*128;
    if (id < 3*128*128){
        int l = id / (128*128);
        int rem = id % (128*128);
        int n = rem >> 7, k = rem & 127;
        wUe2w[id] = f2bf(Wue2[((size_t)l*128 + k)*128 + n]);
        return;
    }
    id -= 3*128*128;
    if (id < 3*256*256){
        int l = id / (256*256);
        int rem = id % (256*256);
        int n = rem >> 8, k = rem & 255;
        wM2w[id] = f2bf(Wm2[((size_t)l*256 + k)*256 + n]);
    }
}

// ---------------- MFMA GEMM helpers (templated tile sizes) ----------------
template<int NR>
__device__ __forceinline__ void stage_tile_t(
    const unsigned short* __restrict__ gbase, int ldg, int k0,
    unsigned short* lds, int tid)
{
    #pragma unroll
    for (int it=0; it<NR/32; ++it){
        int idx = it*256 + tid;
        int row = idx >> 3;
        int ke  = (idx & 7) * 8;
        const float4* src = (const float4*)(gbase + (size_t)row*ldg + k0 + ke);
        *(float4*)(&lds[row*LDA + ke]) = *src;
    }
}

// normal orientation: acc row = wm*(TI*16)+i*16+quad*4+rg, col = wn*(TJ*16)+j*16+cl
template<int TI, int TJ>
__device__ __forceinline__ void mma_tile_t(
    const unsigned short* Als, const unsigned short* Bls,
    int wm, int wn, int lane, floatx4 acc[TI][TJ])
{
    #pragma unroll
    for (int s=0; s<2; ++s){
        short8 af[TI], bf[TJ];
        int kidx = s*32 + (lane>>4)*8;
        #pragma unroll
        for (int t=0;t<TI;++t){
            int row = wm*(TI*16) + t*16 + (lane&15);
            af[t] = *(const short8*)(&Als[row*LDA + kidx]);
        }
        #pragma unroll
        for (int t=0;t<TJ;++t){
            int col = wn*(TJ*16) + t*16 + (lane&15);
            bf[t] = *(const short8*)(&Bls[col*LDA + kidx]);
        }
        #pragma unroll
        for (int i=0;i<TI;++i)
            #pragma unroll
            for (int j=0;j<TJ;++j)
                acc[i][j] = __builtin_amdgcn_mfma_f32_16x16x32_bf16(af[i], bf[j], acc[i][j], 0,0,0);
    }
}

// swapped orientation: acc row = wm*(TI*16)+i*16+cl, col = wn*(TJ*16)+j*16+quad*4+rg
template<int TI, int TJ>
__device__ __forceinline__ void mma_tile_sw(
    const unsigned short* Als, const unsigned short* Bls,
    int wm, int wn, int lane, floatx4 acc[TI][TJ])
{
    #pragma unroll
    for (int s=0; s<2; ++s){
        short8 af[TI], bf[TJ];
        int kidx = s*32 + (lane>>4)*8;
        #pragma unroll
        for (int t=0;t<TI;++t){
            int row = wm*(TI*16) + t*16 + (lane&15);
            af[t] = *(const short8*)(&Als[row*LDA + kidx]);
        }
        #pragma unroll
        for (int t=0;t<TJ;++t){
            int col = wn*(TJ*16) + t*16 + (lane&15);
            bf[t] = *(const short8*)(&Bls[col*LDA + kidx]);
        }
        #pragma unroll
        for (int i=0;i<TI;++i)
            #pragma unroll
            for (int j=0;j<TJ;++j)
                acc[i][j] = __builtin_amdgcn_mfma_f32_16x16x32_bf16(bf[j], af[i], acc[i][j], 0,0,0);
    }
}

// A from LDP-stride tile (K=128 resident), B from 64-wide chunk — normal orientation
__device__ __forceinline__ void mma_tileA_lp(
    const unsigned short* Atile, const unsigned short* Bls,
    int k0, int wm, int wn, int lane, floatx4 acc[4][4])
{
    #pragma unroll
    for (int s=0; s<2; ++s){
        short8 af[4], bf[4];
        int kloc = s*32 + (lane>>4)*8;
        #pragma unroll
        for (int t=0;t<4;++t){
            int row = wm*64 + t*16 + (lane&15);
            af[t] = *(const short8*)(&Atile[row*LDP + k0 + kloc]);
            int col = wn*64 + t*16 + (lane&15);
            bf[t] = *(const short8*)(&Bls[col*LDA + kloc]);
        }
        #pragma unroll
        for (int i=0;i<4;++i)
            #pragma unroll
            for (int j=0;j<4;++j)
                acc[i][j] = __builtin_amdgcn_mfma_f32_16x16x32_bf16(af[i], bf[j], acc[i][j], 0,0,0);
    }
}

// ---------------- K-PQ: PQ(bf16) = node_bf @ wPQw^T + bias (swapped C-layout) ----------------
__global__ __launch_bounds__(256) void k_pq(
    const unsigned short* __restrict__ A, const unsigned short* __restrict__ Bw,
    unsigned short* __restrict__ PQbf,
    const float* __restrict__ bm1l, const float* __restrict__ bue1l)
{
    __shared__ __align__(16) unsigned short smem[(64+128)*LDA];  // 27648 B
    unsigned short* Als = smem;
    unsigned short* Bls = smem + 64*LDA;
    unsigned short* tile = smem;            // 64*LDP, reuse after GEMM
    int tid = threadIdx.x;
    int lane = tid & 63, wave = tid >> 6;
    int wm = wave >> 1, wn = wave & 1;      // wave tile 32 x 64
    const unsigned short* Ab = A + (size_t)blockIdx.x*64*256;
    const unsigned short* Bb = Bw + (size_t)blockIdx.y*128*256;
    floatx4 acc[2][4];
    #pragma unroll
    for (int i=0;i<2;++i)
        #pragma unroll
        for (int j=0;j<4;++j) acc[i][j] = (floatx4){0.f,0.f,0.f,0.f};
    for (int k0=0; k0<256; k0+=BK){
        stage_tile_t<64>(Ab, 256, k0, Als, tid);
        stage_tile_t<128>(Bb, 256, k0, Bls, tid);
        __syncthreads();
        mma_tile_sw<2,4>(Als, Bls, wm, wn, lane, acc);
        __syncthreads();
    }
    int quad = lane >> 4, cl = lane & 15;
    #pragma unroll
    for (int i=0;i<2;++i){
        int rowl = wm*32 + i*16 + cl;
        #pragma unroll
        for (int j=0;j<4;++j){
            int coll = wn*64 + j*16 + quad*4;
            int col0 = blockIdx.y*128 + coll;
            float4 bv;
            if (col0 < 256)      bv = *(const float4*)&bm1l[col0];
            else if (col0 < 384) bv = *(const float4*)&bue1l[col0-256];
            else                 bv = (float4){0.f,0.f,0.f,0.f};
            sh4 w;
            w[0] = (short)f2bf(acc[i][j][0] + bv.x);
            w[1] = (short)f2bf(acc[i][j][1] + bv.y);
            w[2] = (short)f2bf(acc[i][j][2] + bv.z);
            w[3] = (short)f2bf(acc[i][j][3] + bv.w);
            *(sh4*)(&tile[rowl*LDP + coll]) = w;
        }
    }
    __syncthreads();
    {
        int rl = tid >> 2;                  // 0..63
        int h  = tid & 3;                   // 32-col chunk
        unsigned short* dst = PQbf + (size_t)(blockIdx.x*64 + rl)*768 + blockIdx.y*128 + h*32;
        #pragma unroll
        for (int q=0; q<4; ++q)
            *(short8*)(dst + q*8) = *(const short8*)(&tile[rl*LDP + h*32 + q*8]);
    }
}

// ---------------- K4 FUSED: S path (y=0,1) + edge path (y=2) in one launch ----------------
// edge path reads edge_cur (Apad), writes edge_nxt (double buffer) -> no hazard with S path.
__global__ __launch_bounds__(256) void k_h1(
    const unsigned short* __restrict__ Apad,   // edge_pad current
    const unsigned short* __restrict__ BwAll,  // wEw layer base (384 out-cols x 128)
    const unsigned short* __restrict__ BwU2,
    const unsigned short* __restrict__ PQbf, const int* __restrict__ jg_pad,
    const float* __restrict__ mask_pad, const float* __restrict__ bue2l,
    unsigned short* __restrict__ Sout,
    unsigned short* __restrict__ edge_nxt, float* __restrict__ edge_f32,
    int last)
{
    __shared__ __align__(16) unsigned short smem[26624];   // 53248 B (max of both paths)
    __shared__ float smask[128];

    int bid = blockIdx.x;
    int y   = bid % 3;            // 0,1 -> S path colblk; 2 -> edge path (interleaved)
    int bx  = bid / 3;

    int tid = threadIdx.x;
    int lane = tid & 63, wave = tid >> 6;
    int wm = wave >> 1, wn = wave & 1;
    int quad = lane >> 4, cl = lane & 15;

    if (y < 2){
        // ================= S path (colblk = y) =================
        unsigned short* Als = smem;
        unsigned short* Bls = smem + 128*LDA;
        unsigned short* pqT = smem;             // transposed tile [col][row], reuse after GEMM
        int colblk = y;

        const unsigned short* Ab = Apad + (size_t)bx*128*128;
        const unsigned short* Bb = BwAll + (size_t)colblk*128*128;
        floatx4 acc[4][4];
        #pragma unroll
        for (int i=0;i<4;++i)
            #pragma unroll
            for (int j=0;j<4;++j) acc[i][j] = (floatx4){0.f,0.f,0.f,0.f};
        for (int k0=0; k0<128; k0+=BK){
            stage_tile_t<128>(Ab, 128, k0, Als, tid);
            stage_tile_t<128>(Bb, 128, k0, Bls, tid);
            __syncthreads();
            mma_tile_t<4,4>(Als, Bls, wm, wn, lane, acc);
            __syncthreads();
        }

        // transposed PQ gather: work item = 4 rows x 8 cols
        {
            int colbase = colblk*128;
            #pragma unroll
            for (int it=0; it<2; ++it){
                int w    = it*256 + tid;
                int rq   = w & 31;              // 4-row block
                int c8   = w >> 5;              // 8-col block
                int row0 = rq*4;
                int r0   = bx*128 + row0;
                int ni   = r0 >> 5;             // same node for all 4 rows
                int4 jg4 = *(const int4*)&jg_pad[r0];
                int colg = colbase + c8*8;
                short8 pv = *(const short8*)(PQbf + (size_t)ni*768 + colg);
                short8 q0 = *(const short8*)(PQbf + (size_t)jg4.x*768 + 384 + colg);
                short8 q1 = *(const short8*)(PQbf + (size_t)jg4.y*768 + 384 + colg);
                short8 q2 = *(const short8*)(PQbf + (size_t)jg4.z*768 + 384 + colg);
                short8 q3 = *(const short8*)(PQbf + (size_t)jg4.w*768 + 384 + colg);
                #pragma unroll
                for (int q=0; q<8; ++q){
                    float pf = bf2f((unsigned short)pv[q]);
                    sh4 ov;
                    ov[0] = (short)f2bf(pf + bf2f((unsigned short)q0[q]));
                    ov[1] = (short)f2bf(pf + bf2f((unsigned short)q1[q]));
                    ov[2] = (short)f2bf(pf + bf2f((unsigned short)q2[q]));
                    ov[3] = (short)f2bf(pf + bf2f((unsigned short)q3[q]));
                    *(sh4*)(&pqT[(c8*8 + q)*LDP + row0]) = ov;
                }
            }
            if (tid < 128) smask[tid] = mask_pad[bx*128 + tid];
        }
        __syncthreads();

        float sumA[4] = {0.f,0.f,0.f,0.f};
        float sumB[4] = {0.f,0.f,0.f,0.f};
        #pragma unroll
        for (int i=0;i<4;++i){
            int rowl0 = wm*64 + i*16 + quad*4;
            float4 mk = *(const float4*)&smask[rowl0];
            float mkv[4] = {mk.x, mk.y, mk.z, mk.w};
            #pragma unroll
            for (int j=0;j<4;++j){
                int coll = wn*64 + j*16 + cl;
                sh4 pq4 = *(const sh4*)(&pqT[coll*LDP + rowl0]);
                #pragma unroll
                for (int rg=0; rg<4; ++rg){
                    float v  = softplusf(acc[i][j][rg] + bf2f((unsigned short)pq4[rg]));
                    float mv = mkv[rg]*v;
                    if (i < 2) sumA[j] += mv; else sumB[j] += mv;
                }
            }
        }

        // rows wm*64..wm*64+63 = nodes (bx*4 + 2wm), (bx*4 + 2wm + 1)
        int nodeA = bx*4 + wm*2;
        #pragma unroll
        for (int j=0;j<4;++j){
            float a = sumA[j];
            a += __shfl_xor(a, 16, 64);
            a += __shfl_xor(a, 32, 64);
            float b = sumB[j];
            b += __shfl_xor(b, 16, 64);
            b += __shfl_xor(b, 32, 64);
            int col = colblk*128 + wn*64 + j*16 + cl;
            if (quad == 0)      Sout[(size_t)nodeA*256 + col]     = f2bf(a);
            else if (quad == 1) Sout[(size_t)(nodeA+1)*256 + col] = f2bf(b);
        }
    } else {
        // ================= edge path =================
        unsigned short* Als  = smem;
        unsigned short* Bls  = smem + 128*LDA;      // +9216
        unsigned short* tile = smem;                // 128*LDP = 17408 shorts
        unsigned short* B2   = smem + 128*LDP;      // +17408 .. 26624
        const unsigned short* BwE = BwAll + (size_t)2*128*128;

        const unsigned short* Ab = Apad + (size_t)bx*128*128;
        floatx4 acc[4][4];
        #pragma unroll
        for (int i=0;i<4;++i)
            #pragma unroll
            for (int j=0;j<4;++j) acc[i][j] = (floatx4){0.f,0.f,0.f,0.f};
        for (int k0=0; k0<128; k0+=BK){
            stage_tile_t<128>(Ab, 128, k0, Als, tid);
            stage_tile_t<128>(BwE, 128, k0, Bls, tid);
            __syncthreads();
            mma_tile_t<4,4>(Als, Bls, wm, wn, lane, acc);
            __syncthreads();
        }

        // early-issue GEMM2 first weight chunk (hides under gather+softplus)
        stage_tile_t<128>(BwU2, 128, 0, B2, tid);

        // PQ gather (row-major, cols 256..383) into tile
        {
            int rl = tid >> 1;
            int h  = tid & 1;
            int r  = bx*128 + rl;
            int ni = r >> 5;
            int jg = jg_pad[r];
            int cb = 256 + h*64;
            const unsigned short* Pr = PQbf + (size_t)ni*768 + cb;
            const unsigned short* Qr = PQbf + (size_t)jg*768 + 384 + cb;
            #pragma unroll
            for (int q=0; q<8; ++q){
                short8 pv = *(const short8*)(Pr + q*8);
                short8 qv = *(const short8*)(Qr + q*8);
                short8 ov;
                #pragma unroll
                for (int z=0; z<8; ++z)
                    ov[z] = (short)f2bf(bf2f((unsigned short)pv[z]) + bf2f((unsigned short)qv[z]));
                *(short8*)(&tile[rl*LDP + h*64 + q*8]) = ov;
            }
        }
        __syncthreads();

        // softplus(acc + PQ) in place (sole-owner slots, normal orientation)
        #pragma unroll
        for (int i=0;i<4;++i){
            #pragma unroll
            for (int rg=0;rg<4;++rg){
                int rowl = wm*64 + i*16 + quad*4 + rg;
                #pragma unroll
                for (int j=0;j<4;++j){
                    int coll = wn*64 + j*16 + cl;
                    float pq = bf2f(tile[rowl*LDP + coll]);
                    float v  = softplusf(acc[i][j][rg] + pq);
                    tile[rowl*LDP + coll] = f2bf(v);
                }
            }
        }
        __syncthreads();

        // GEMM2: acc2 = H1(tile) @ Wue2
        floatx4 acc2[4][4];
        #pragma unroll
        for (int i=0;i<4;++i)
            #pragma unroll
            for (int j=0;j<4;++j) acc2[i][j] = (floatx4){0.f,0.f,0.f,0.f};
        mma_tileA_lp(tile, B2, 0, wm, wn, lane, acc2);
        __syncthreads();                            // B2(0) free
        stage_tile_t<128>(BwU2, 128, 64, B2, tid);
        __syncthreads();
        mma_tileA_lp(tile, B2, 64, wm, wn, lane, acc2);
        __syncthreads();                            // tile & B2 free

        // write acc2 into tile; load bias into dead B2 space
        float* sbias = (float*)B2;
        #pragma unroll
        for (int i=0;i<4;++i){
            #pragma unroll
            for (int rg=0;rg<4;++rg){
                int rowl = wm*64 + i*16 + quad*4 + rg;
                #pragma unroll
                for (int j=0;j<4;++j){
                    int coll = wn*64 + j*16 + cl;
                    tile[rowl*LDP + coll] = f2bf(acc2[i][j][rg]);
                }
            }
        }
        if (tid < 128) sbias[tid] = bue2l[tid];
        __syncthreads();

        // edge residual epilogue: read old from Apad(cur), write to edge_nxt / f32 out
        if (last){
            int c16  = lane & 31;
            int rsub = lane >> 5;
            #pragma unroll
            for (int step=0; step<16; ++step){
                int rowl = wave*32 + step*2 + rsub;
                int R = bx*128 + rowl;
                int k = R & (KP-1);
                if (k < Kn){
                    float mij = mask_pad[R];
                    int node = R >> 5;
                    int e = node*Kn + k;
                    sh4 ov = *(const sh4*)(Apad + (size_t)R*128 + c16*4);
                    sh4 av = *(const sh4*)(&tile[rowl*LDP + c16*4]);
                    float4 bv = *(const float4*)(&sbias[c16*4]);
                    float4 f;
                    f.x = (bf2f((unsigned short)ov[0]) + bf2f((unsigned short)av[0]) + bv.x)*mij;
                    f.y = (bf2f((unsigned short)ov[1]) + bf2f((unsigned short)av[1]) + bv.y)*mij;
                    f.z = (bf2f((unsigned short)ov[2]) + bf2f((unsigned short)av[2]) + bv.z)*mij;
                    f.w = (bf2f((unsigned short)ov[3]) + bf2f((unsigned short)av[3]) + bv.w)*mij;
                    *(float4*)(edge_f32 + (size_t)e*128 + c16*4) = f;
                }
            }
        } else {
            int c8   = lane & 15;
            int rsub = lane >> 4;
            #pragma unroll
            for (int step=0; step<8; ++step){
                int rowl = wave*32 + step*4 + rsub;
                int R = bx*128 + rowl;
                int k = R & (KP-1);
                unsigned short* ep = edge_nxt + (size_t)R*128 + c8*8;
                if (k < Kn){
                    float mij = mask_pad[R];
                    short8 ov = *(const short8*)(Apad + (size_t)R*128 + c8*8);
                    short8 av = *(const short8*)(&tile[rowl*LDP + c8*8]);
                    float4 b0 = *(const float4*)(&sbias[c8*8]);
                    float4 b1 = *(const float4*)(&sbias[c8*8 + 4]);
                    float nv[8];
                    nv[0] = (bf2f((unsigned short)ov[0]) + bf2f((unsigned short)av[0]) + b0.x)*mij;
                    nv[1] = (bf2f((unsigned short)ov[1]) + bf2f((unsigned short)av[1]) + b0.y)*mij;
                    nv[2] = (bf2f((unsigned short)ov[2]) + bf2f((unsigned short)av[2]) + b0.z)*mij;
                    nv[3] = (bf2f((unsigned short)ov[3]) + bf2f((unsigned short)av[3]) + b0.w)*mij;
                    nv[4] = (bf2f((unsigned short)ov[4]) + bf2f((unsigned short)av[4]) + b1.x)*mij;
                    nv[5] = (bf2f((unsigned short)ov[5]) + bf2f((unsigned short)av[5]) + b1.y)*mij;
                    nv[6] = (bf2f((unsigned short)ov[6]) + bf2f((unsigned short)av[6]) + b1.z)*mij;
                    nv[7] = (bf2f((unsigned short)ov[7]) + bf2f((unsigned short)av[7]) + b1.w)*mij;
                    short8 sv;
                    #pragma unroll
                    for (int z=0; z<8; ++z) sv[z] = (short)f2bf(nv[z]);
                    *(short8*)ep = sv;
                } else {
                    // zero pad rows of the next buffer (never initialized otherwise)
                    short8 z = {0,0,0,0,0,0,0,0};
                    *(short8*)ep = z;
                }
            }
        }
    }
}

// ---------------- K5: node update (swapped C-layout, vectorized epilogue) ----------------
__global__ __launch_bounds__(256) void k_node_gemm(
    const unsigned short* __restrict__ S, const unsigned short* __restrict__ Bw,
    const float* __restrict__ bm2l, const float* __restrict__ cnt,
    const float* __restrict__ mask_i,
    float* __restrict__ node_h, unsigned short* __restrict__ node_bf)
{
    __shared__ __align__(16) unsigned short Als[64*LDA];
    __shared__ __align__(16) unsigned short Bls[64*LDA];
    int tid = threadIdx.x;
    int lane = tid & 63, wave = tid >> 6;
    int wm = wave >> 1, wn = wave & 1;      // wave tile 32 x 32
    const unsigned short* Ab = S + (size_t)blockIdx.x*64*256;
    const unsigned short* Bb = Bw + (size_t)blockIdx.y*64*256;
    floatx4 acc[2][2];
    #pragma unroll
    for (int i=0;i<2;++i)
        #pragma unroll
        for (int j=0;j<2;++j) acc[i][j] = (floatx4){0.f,0.f,0.f,0.f};
    for (int k0=0; k0<256; k0+=BK){
        stage_tile_t<64>(Ab, 256, k0, Als, tid);
        stage_tile_t<64>(Bb, 256, k0, Bls, tid);
        __syncthreads();
        mma_tile_sw<2,2>(Als, Bls, wm, wn, lane, acc);
        __syncthreads();
    }
    int quad = lane >> 4, cl = lane & 15;
    #pragma unroll
    for (int i=0;i<2;++i){
        int nid = blockIdx.x*64 + wm*32 + i*16 + cl;
        float ct = cnt[nid];
        float mi = mask_i[nid];
        float dv = ct + EPSF;
        #pragma unroll
        for (int j=0;j<2;++j){
            int col = blockIdx.y*64 + wn*32 + j*16 + quad*4;
            float4 bv = *(const float4*)&bm2l[col];
            float4 nh = *(const float4*)&node_h[(size_t)nid*256 + col];
            float4 r;
            r.x = (nh.x + (acc[i][j][0] + ct*bv.x)/dv)*mi;
            r.y = (nh.y + (acc[i][j][1] + ct*bv.y)/dv)*mi;
            r.z = (nh.z + (acc[i][j][2] + ct*bv.z)/dv)*mi;
            r.w = (nh.w + (acc[i][j][3] + ct*bv.w)/dv)*mi;
            *(float4*)&node_h[(size_t)nid*256 + col] = r;
            sh4 w;
            w[0] = (short)f2bf(r.x);
            w[1] = (short)f2bf(r.y);
            w[2] = (short)f2bf(r.z);
            w[3] = (short)f2bf(r.w);
            *(sh4*)&node_bf[(size_t)nid*256 + col] = w;
        }
    }
}

extern "C" void kernel_launch(void* const* d_in, const int* in_sizes, int n_in,
                              void* d_out, int out_size, void* d_ws, size_t ws_size,
                              hipStream_t stream)
{
    (void)in_sizes; (void)n_in; (void)out_size; (void)ws_size;
    const float* X   = (const float*)d_in[0];
    const int*   C   = (const int*)  d_in[1];
    const float* Wn  = (const float*)d_in[2];
    const float* bn  = (const float*)d_in[3];
    const float* We  = (const float*)d_in[4];
    const float* be  = (const float*)d_in[5];
    const float* Wm1 = (const float*)d_in[6];
    const float* bm1 = (const float*)d_in[7];
    const float* Wm2 = (const float*)d_in[8];
    const float* bm2 = (const float*)d_in[9];
    const float* Wue1= (const float*)d_in[10];
    const float* bue1= (const float*)d_in[11];
    const float* Wue2= (const float*)d_in[12];
    const float* bue2= (const float*)d_in[13];

    float* out       = (float*)d_out;
    float* out_node  = out;                    // (B,N,DN)    1048576
    float* out_edge  = out + 1048576;          // (B,N,K,DE) 15728640
    float* out_eidxf = out + 16777216;         // (B,N,K)      122880
    float* out_maski = out + 16900096;         // (B,N)          4096
    float* out_maskij= out + 16904192;         // (B,N,K)      122880

    char* wsb = (char*)d_ws;
    size_t off = 0;
    float* wXc    = (float*)(wsb + off); off += (size_t)12288*4;
    float* wR     = (float*)(wsb + off); off += (size_t)36864*4;
    float* wF     = (float*)(wsb + off); off += (size_t)49152*4;
    int*   wEidx  = (int*)  (wsb + off); off += (size_t)EDGES*4;
    int*   wJgPad = (int*)  (wsb + off); off += (size_t)RPAD*4;
    float* wMaskP = (float*)(wsb + off); off += (size_t)RPAD*4;
    float* wCnt   = (float*)(wsb + off); off += (size_t)NODES*4;
    unsigned short* wPQ      = (unsigned short*)(wsb + off); off += (size_t)NODES*768*2;
    unsigned short* wS       = (unsigned short*)(wsb + off); off += (size_t)NODES*256*2;
    unsigned short* wNodeBf  = (unsigned short*)(wsb + off); off += (size_t)NODES*256*2;
    unsigned short* wEdgePadA= (unsigned short*)(wsb + off); off += (size_t)RPAD*128*2;
    unsigned short* wEdgePadB= (unsigned short*)(wsb + off); off += (size_t)RPAD*128*2;
    unsigned short* wFeatP   = (unsigned short*)(wsb + off); off += (size_t)RPAD*32*2;
    unsigned short* wWe0     = (unsigned short*)(wsb + off); off += (size_t)128*32*2;
    unsigned short* wPQw     = (unsigned short*)(wsb + off); off += (size_t)3*768*256*2;
    unsigned short* wEw      = (unsigned short*)(wsb + off); off += (size_t)3*384*128*2;
    unsigned short* wUe2w    = (unsigned short*)(wsb + off); off += (size_t)3*128*128*2;
    unsigned short* wM2w     = (unsigned short*)(wsb + off); off += (size_t)3*256*256*2;

    unsigned short* eb[2] = { wEdgePadA, wEdgePadB };

    k_geom <<<16,    256, 0, stream>>>(X, C, wXc, wR, wF, out_maski);
    k_nodeh<<<NODES, 256, 0, stream>>>(wF, Wn, bn, C, out_node, wNodeBf);
    k_knn  <<<NODES/4, 256, 0, stream>>>(wXc, C, wEidx, out_eidxf);

    k_pack_all<<<3856, 256, 0, stream>>>(We, Wm1, Wue1, Wue2, Wm2,
                                         wWe0, wPQw, wEw, wUe2w, wM2w);
    k_edge_feat<<<RPAD/256, 256, 0, stream>>>(wXc, wR, wEidx, C, wFeatP,
                                              out_maskij, wMaskP, wJgPad, wCnt);
    k_edge0<<<RPAD/128, 256, 0, stream>>>(wFeatP, wWe0, be, wMaskP, wEdgePadA);

    for (int l=0; l<3; ++l){
        k_pq<<<dim3(64,6), 256, 0, stream>>>(wNodeBf, wPQw + (size_t)l*768*256, wPQ,
                                             bm1 + l*256, bue1 + l*128);
        k_h1<<<3*(RPAD/128), 256, 0, stream>>>(
            eb[l&1], wEw + (size_t)l*384*128, wUe2w + (size_t)l*128*128,
            wPQ, wJgPad, wMaskP, bue2 + l*128,
            wS, eb[(l+1)&1], out_edge, (l==2) ? 1 : 0);
        k_node_gemm<<<dim3(NODES/64,4), 256, 0, stream>>>(
            wS, wM2w + (size_t)l*256*256, bm2 + l*256, wCnt, out_maski,
            out_node, wNodeBf);
    }
}

// Round 6
// 443.136 us; speedup vs baseline: 1.1739x; 1.1739x over previous
//
#include <hip/hip_runtime.h>
#include <math.h>

#define Bdim 2
#define Nn   2048
#define Kn   30
#define KP   32                   // padded edges per node
#define DNc  256
#define DEc  128
#define NODES (Bdim*Nn)           // 4096
#define EDGES (Bdim*Nn*Kn)        // 122880
#define RPAD  (NODES*KP)          // 131072 padded edge rows
#define EPSF 1e-6f

#define BK 64
#define LDA (BK+8)    // padded GEMM LDS row (bf16 elems)
#define LDA0 40       // padded K=32 GEMM LDS row
#define LDP 136       // LDS tile row stride (shorts), 16B-aligned rows

typedef __attribute__((ext_vector_type(8))) short short8;
typedef __attribute__((ext_vector_type(4))) short sh4;
typedef __attribute__((ext_vector_type(4))) float floatx4;

__device__ __forceinline__ float softplusf(float x){
    float e = __expf(-fabsf(x));
    return fmaxf(x, 0.f) + __logf(1.f + e);
}

__device__ __forceinline__ unsigned short f2bf(float x){
    union { float f; unsigned u; } v; v.f = x;
    unsigned r = v.u + 0x7fff + ((v.u >> 16) & 1);   // RNE
    return (unsigned short)(r >> 16);
}
__device__ __forceinline__ float bf2f(unsigned short h){
    union { unsigned u; float f; } v; v.u = ((unsigned)h) << 16;
    return v.f;
}

// ---------------- K1: per-node geometry ----------------
__global__ __launch_bounds__(256) void k_geom(
    const float* __restrict__ X, const int* __restrict__ C,
    float* __restrict__ Xc, float* __restrict__ Rm,
    float* __restrict__ feat, float* __restrict__ mask_out)
{
    int id = blockIdx.x*256 + threadIdx.x;
    if (id >= NODES) return;
    float a[4][3];
    #pragma unroll
    for (int t=0;t<4;++t)
        #pragma unroll
        for (int d=0;d<3;++d) a[t][d] = X[id*12 + t*3 + d];
    #pragma unroll
    for (int d=0; d<3; ++d){
        float s = __fadd_rn(__fadd_rn(__fadd_rn(a[0][d],a[1][d]),a[2][d]),a[3][d]);
        Xc[id*3+d] = __fmul_rn(s, 0.25f);
    }
    mask_out[id] = (C[id] > 0) ? 1.f : 0.f;

    float u[3], v[3], w[3], b2[3], v0[3], vv[3];
    #pragma unroll
    for (int d=0;d<3;++d) b2[d] = a[2][d]-a[1][d];
    float n2 = sqrtf(b2[0]*b2[0]+b2[1]*b2[1]+b2[2]*b2[2]);
    #pragma unroll
    for (int d=0;d<3;++d) u[d] = b2[d]/(n2+EPSF);
    #pragma unroll
    for (int d=0;d<3;++d) v0[d] = a[0][d]-a[1][d];
    float dt = v0[0]*u[0]+v0[1]*u[1]+v0[2]*u[2];
    #pragma unroll
    for (int d=0;d<3;++d) vv[d] = v0[d] - dt*u[d];
    float nv = sqrtf(vv[0]*vv[0]+vv[1]*vv[1]+vv[2]*vv[2]);
    #pragma unroll
    for (int d=0;d<3;++d) v[d] = vv[d]/(nv+EPSF);
    w[0] = u[1]*v[2]-u[2]*v[1];
    w[1] = u[2]*v[0]-u[0]*v[2];
    w[2] = u[0]*v[1]-u[1]*v[0];
    #pragma unroll
    for (int d=0;d<3;++d){
        Rm[id*9 + d*3 + 0] = u[d];
        Rm[id*9 + d*3 + 1] = v[d];
        Rm[id*9 + d*3 + 2] = w[d];
    }
    float bonds[3][3];
    #pragma unroll
    for (int d=0;d<3;++d){
        bonds[0][d] = a[1][d]-a[0][d];
        bonds[1][d] = b2[d];
        bonds[2][d] = a[3][d]-a[2][d];
    }
    #pragma unroll
    for (int bi=0;bi<3;++bi){
        float nb = sqrtf(bonds[bi][0]*bonds[bi][0]+bonds[bi][1]*bonds[bi][1]+bonds[bi][2]*bonds[bi][2]);
        #pragma unroll
        for (int d=0;d<3;++d) feat[id*12 + bi*4 + d] = bonds[bi][d]/(nb+EPSF);
        feat[id*12 + bi*4 + 3] = logf(nb+EPSF);
    }
}

// ---------------- K1b: node_h init (f32 + bf16) ----------------
__global__ __launch_bounds__(256) void k_nodeh(
    const float* __restrict__ feat, const float* __restrict__ Wn,
    const float* __restrict__ bn, const int* __restrict__ C,
    float* __restrict__ node_h, unsigned short* __restrict__ node_bf)
{
    int nid = blockIdx.x;
    int c   = threadIdx.x;
    __shared__ float f[12];
    if (c < 12) f[c] = feat[nid*12 + c];
    __syncthreads();
    float acc = bn[c];
    #pragma unroll
    for (int k=0;k<12;++k) acc += f[k]*Wn[k*DNc + c];
    float mask = (C[nid] > 0) ? 1.f : 0.f;
    float r = acc*mask;
    node_h[nid*DNc + c] = r;
    node_bf[nid*DNc + c] = f2bf(r);
}

// ---------------- K2: kNN top-30, wave-per-node, register selection ----------------
__global__ __launch_bounds__(256) void k_knn(
    const float* __restrict__ Xc, const int* __restrict__ C,
    int* __restrict__ eidx, float* __restrict__ eidx_f)
{
    __shared__ float sx[Nn], sy[Nn], sz[Nn], sadd[Nn];
    int tid  = threadIdx.x;
    int lane = tid & 63, wave = tid >> 6;
    int node0 = blockIdx.x*4;            // 4 nodes per block, same batch
    int base  = (node0 >> 11) << 11;     // batch base node
    for (int j=tid; j<Nn; j+=256){
        int gj = base + j;
        sx[j] = Xc[gj*3+0]; sy[j] = Xc[gj*3+1]; sz[j] = Xc[gj*3+2];
        sadd[j] = (C[gj] > 0) ? 0.f : 1e9f;
    }
    __syncthreads();

    int node = node0 + wave;
    int iloc = node & (Nn-1);
    float xi = sx[iloc], yi = sy[iloc], zi = sz[iloc];

    unsigned long long kreg[32];
    unsigned long long gm[8];
    #pragma unroll
    for (int t=0; t<32; ++t){
        int j = lane + t*64;
        float dx = __fsub_rn(xi, sx[j]);
        float dy = __fsub_rn(yi, sy[j]);
        float dz = __fsub_rn(zi, sz[j]);
        float vv = __fadd_rn(__fadd_rn(__fmul_rn(dx,dx),__fmul_rn(dy,dy)),__fmul_rn(dz,dz));
        vv = __fadd_rn(vv, sadd[j]);
        if (j == iloc) vv = __fadd_rn(vv, 1e9f);
        union { float f; unsigned u; } cv; cv.f = vv;
        kreg[t] = (((unsigned long long)cv.u) << 11) | (unsigned)j;
    }
    #pragma unroll
    for (int g=0; g<8; ++g){
        unsigned long long a = kreg[4*g+0], b = kreg[4*g+1];
        unsigned long long c = kreg[4*g+2], d = kreg[4*g+3];
        unsigned long long m1 = a<b?a:b, m2 = c<d?c:d;
        gm[g] = m1<m2?m1:m2;
    }
    unsigned long long m = gm[0]; int marg = 0;
    #pragma unroll
    for (int g=1; g<8; ++g) if (gm[g] < m){ m = gm[g]; marg = g; }

    for (int kk=0; kk<Kn; ++kk){
        unsigned long long best = m;
        #pragma unroll
        for (int d=1; d<64; d<<=1){
            unsigned long long o = __shfl_xor(best, d, 64);
            if (o < best) best = o;
        }
        if (lane == 0){
            int j = (int)(best & 2047ull);
            eidx  [(size_t)node*Kn + kk] = j;
            eidx_f[(size_t)node*Kn + kk] = (float)j;
        }
        if (m == best){
            #pragma unroll
            for (int g=0; g<8; ++g){
                if (marg == g){
                    #pragma unroll
                    for (int t=0; t<4; ++t)
                        if (kreg[4*g+t] == best) kreg[4*g+t] = ~0ull;
                    unsigned long long a = kreg[4*g+0], b = kreg[4*g+1];
                    unsigned long long c = kreg[4*g+2], d = kreg[4*g+3];
                    unsigned long long m1 = a<b?a:b, m2 = c<d?c:d;
                    gm[g] = m1<m2?m1:m2;
                }
            }
            m = gm[0]; marg = 0;
            #pragma unroll
            for (int g=1; g<8; ++g) if (gm[g] < m){ m = gm[g]; marg = g; }
        }
    }
}

// ---------------- K3a: edge features, one thread per padded edge slot ----------------
__global__ __launch_bounds__(256) void k_edge_feat(
    const float* __restrict__ Xc, const float* __restrict__ Rm,
    const int* __restrict__ eidx, const int* __restrict__ C,
    unsigned short* __restrict__ featp,
    float* __restrict__ mask_ij_out, float* __restrict__ mask_pad,
    int* __restrict__ jg_pad, float* __restrict__ cnt)
{
    int r   = blockIdx.x*256 + threadIdx.x;      // padded edge row
    int nid = r >> 5;
    int k   = r & 31;
    int b   = nid >> 11;
    float mij = 0.f;
    int   jb  = nid;
    float f[28];
    if (k < Kn){
        int e = nid*Kn + k;
        int j = eidx[e];
        jb = (b<<11) + j;
        mij = (C[nid] > 0 && C[jb] > 0) ? 1.f : 0.f;
        mask_ij_out[e] = mij;
        float xi0 = Xc[nid*3+0], xi1 = Xc[nid*3+1], xi2 = Xc[nid*3+2];
        float d0  = Xc[jb*3+0]-xi0;
        float d1  = Xc[jb*3+1]-xi1;
        float d2v = Xc[jb*3+2]-xi2;
        float dist = sqrtf(d0*d0 + d1*d1 + d2v*d2v);
        float ri[9], rj[9];
        #pragma unroll
        for (int q=0;q<9;++q) ri[q] = Rm[nid*9+q];
        #pragma unroll
        for (int q=0;q<9;++q) rj[q] = Rm[jb*9+q];
        #pragma unroll
        for (int c=0; c<16; ++c){
            float ctr = (20.f/15.f)*(float)c;
            float t = (dist - ctr)*(1.f/1.25f);
            f[c] = expf(-t*t);
        }
        #pragma unroll
        for (int cc=0; cc<3; ++cc){
            float loc = ri[0*3+cc]*d0 + ri[1*3+cc]*d1 + ri[2*3+cc]*d2v;
            f[16+cc] = loc/(dist+EPSF);
        }
        #pragma unroll
        for (int ee=0; ee<3; ++ee)
            #pragma unroll
            for (int ff=0; ff<3; ++ff)
                f[19+ee*3+ff] = ri[0+ee]*rj[0+ff] + ri[3+ee]*rj[3+ff] + ri[6+ee]*rj[6+ff];
    }
    jg_pad[r]   = jb;
    mask_pad[r] = mij;

    // cnt via wave ballot: one wave = exactly 2 nodes (lanes 0-31 / 32-63)
    unsigned long long bal = __ballot(mij > 0.f);
    int lane = threadIdx.x & 63;
    if (lane == 0)  cnt[r >> 5] = (float)__popcll(bal & 0xFFFFFFFFull);
    if (lane == 32) cnt[r >> 5] = (float)__popcll(bal >> 32);

    unsigned short ov[32];
    #pragma unroll
    for (int q=0;q<32;++q) ov[q] = 0;
    if (k < Kn){
        #pragma unroll
        for (int q=0;q<28;++q) ov[q] = f2bf(f[q]);
    }
    unsigned short* dst = featp + (size_t)r*32;
    #pragma unroll
    for (int q=0; q<4; ++q){
        short8 sv;
        #pragma unroll
        for (int z=0; z<8; ++z) sv[z] = (short)ov[q*8+z];
        *(short8*)(dst + q*8) = sv;
    }
}

// ---------------- K3b: E0 = featp @ We^T (K=32) + bias, *mask (swapped C-layout) ----------------
__global__ __launch_bounds__(256) void k_edge0(
    const unsigned short* __restrict__ featp, const unsigned short* __restrict__ Wp,
    const float* __restrict__ be, const float* __restrict__ mask_pad,
    unsigned short* __restrict__ edge_pad)
{
    __shared__ __align__(16) unsigned short smem[128*LDP];   // tile spans whole
    __shared__ float smask[128];
    unsigned short* Als  = smem;               // 128*LDA0 = 5120 shorts
    unsigned short* Bls  = smem + 128*LDA0;    // +5120
    unsigned short* tile = smem;

    int tid = threadIdx.x;
    int lane = tid & 63, wave = tid >> 6;
    int wm = wave >> 1, wn = wave & 1;

    // stage A (128x32) and B^T (128x32)
    {
        const unsigned short* Ab = featp + (size_t)blockIdx.x*128*32;
        #pragma unroll
        for (int it=0; it<2; ++it){
            int idx = it*256 + tid;
            int row = idx >> 2, q = idx & 3;
            *(float4*)(&Als[row*LDA0 + q*8]) = *(const float4*)(Ab + row*32 + q*8);
        }
        if (tid < 128){
            int row = tid;
            *(float4*)(&Bls[row*LDA0 + 0])  = *(const float4*)(Wp + row*32 + 0);
            *(float4*)(&Bls[row*LDA0 + 8])  = *(const float4*)(Wp + row*32 + 8);
            *(float4*)(&Bls[row*LDA0 + 16]) = *(const float4*)(Wp + row*32 + 16);
            *(float4*)(&Bls[row*LDA0 + 24]) = *(const float4*)(Wp + row*32 + 24);
        } else {
            smask[tid-128] = mask_pad[blockIdx.x*128 + (tid-128)];
        }
    }
    __syncthreads();

    floatx4 acc[4][4];
    #pragma unroll
    for (int i=0;i<4;++i)
        #pragma unroll
        for (int j=0;j<4;++j) acc[i][j] = (floatx4){0.f,0.f,0.f,0.f};
    short8 af[4], bf[4];
    int kidx = (lane>>4)*8;
    #pragma unroll
    for (int t=0;t<4;++t){
        int row = wm*64 + t*16 + (lane&15);
        af[t] = *(const short8*)(&Als[row*LDA0 + kidx]);
        int col = wn*64 + t*16 + (lane&15);
        bf[t] = *(const short8*)(&Bls[col*LDA0 + kidx]);
    }
    __syncthreads();                        // all LDS reads done before tile overwrite
    // swapped: acc[i][j]: row = wm*64+i*16+cl, col = wn*64+j*16+quad*4+rg
    #pragma unroll
    for (int i=0;i<4;++i)
        #pragma unroll
        for (int j=0;j<4;++j)
            acc[i][j] = __builtin_amdgcn_mfma_f32_16x16x32_bf16(bf[j], af[i], acc[i][j], 0,0,0);

    int quad = lane >> 4, cl = lane & 15;
    #pragma unroll
    for (int i=0;i<4;++i){
        int rowl = wm*64 + i*16 + cl;
        float mk = smask[rowl];
        #pragma unroll
        for (int j=0;j<4;++j){
            int coll = wn*64 + j*16 + quad*4;
            float4 bv = *(const float4*)&be[coll];
            sh4 w;
            w[0] = (short)f2bf((acc[i][j][0] + bv.x)*mk);
            w[1] = (short)f2bf((acc[i][j][1] + bv.y)*mk);
            w[2] = (short)f2bf((acc[i][j][2] + bv.z)*mk);
            w[3] = (short)f2bf((acc[i][j][3] + bv.w)*mk);
            *(sh4*)(&tile[rowl*LDP + coll]) = w;
        }
    }
    __syncthreads();
    {
        int rl = tid >> 1;
        int h  = tid & 1;
        unsigned short* dst = edge_pad + (size_t)(blockIdx.x*128 + rl)*128 + h*64;
        #pragma unroll
        for (int q=0; q<8; ++q)
            *(short8*)(dst + q*8) = *(const short8*)(&tile[rl*LDP + h*64 + q*8]);
    }
}

// ---------------- single fused weight-pack kernel ----------------
__global__ __launch_bounds__(256) void k_pack_all(
    const float* __restrict__ We, const float* __restrict__ Wm1,
    const float* __restrict__ Wue1, const float* __restrict__ Wue2,
    const float* __restrict__ Wm2,
    unsigned short* __restrict__ wWe0, unsigned short* __restrict__ wPQw,
    unsigned short* __restrict__ wEw, unsigned short* __restrict__ wUe2w,
    unsigned short* __restrict__ wM2w)
{
    int id = blockIdx.x*256 + threadIdx.x;
    if (id < 4096){
        int n = id >> 5, kk = id & 31;
        wWe0[id] = (kk < 28) ? f2bf(We[kk*128 + n]) : 0;
        return;
    }
    id -= 4096;
    if (id < 3*768*256){
        int l = id / (768*256);
        int rem = id % (768*256);
        int n = rem >> 8, k = rem & 255;
        int c = (n < 384) ? n : n - 384;
        int r = (n < 384) ? k : 256 + k;
        float v = (c < 256) ? Wm1[((size_t)l*640 + r)*256 + c]
                            : Wue1[((size_t)l*640 + r)*128 + (c-256)];
        wPQw[id] = f2bf(v);
        return;
    }
    id -= 3*768*256;
    if (id < 3*384*128){
        int l = id / (384*128);
        int rem = id % (384*128);
        int n = rem >> 7, k = rem & 127;
        int r = 512 + k;
        float v = (n < 256) ? Wm1[((size_t)l*640 + r)*256 + n]
                            : Wue1[((size_t)l*640 + r)*128 + (n-256)];
        wEw[id] = f2bf(v);
        return;
    }
    id -= 3*384*128;
    if (id < 3*128*128){
        int l = id / (128*128);
        int rem = id % (128*128);
        int n = rem >> 7, k = rem & 127;
        wUe2w[id] = f2bf(Wue2[((size_t)l*128 + k)*128 + n]);
        return;
    }
    id -= 3*128*128;
    if (id < 3*256*256){
        int l = id / (256*256);
        int rem = id % (256*256);
        int n = rem >> 8, k = rem & 255;
        wM2w[id] = f2bf(Wm2[((size_t)l*256 + k)*256 + n]);
    }
}

// ---------------- MFMA GEMM helpers (templated tile sizes) ----------------
template<int NR>
__device__ __forceinline__ void stage_tile_t(
    const unsigned short* __restrict__ gbase, int ldg, int k0,
    unsigned short* lds, int tid)
{
    #pragma unroll
    for (int it=0; it<NR/32; ++it){
        int idx = it*256 + tid;
        int row = idx >> 3;
        int ke  = (idx & 7) * 8;
        const float4* src = (const float4*)(gbase + (size_t)row*ldg + k0 + ke);
        *(float4*)(&lds[row*LDA + ke]) = *src;
    }
}

// normal orientation: acc row = wm*(TI*16)+i*16+quad*4+rg, col = wn*(TJ*16)+j*16+cl
template<int TI, int TJ>
__device__ __forceinline__ void mma_tile_t(
    const unsigned short* Als, const unsigned short* Bls,
    int wm, int wn, int lane, floatx4 acc[TI][TJ])
{
    #pragma unroll
    for (int s=0; s<2; ++s){
        short8 af[TI], bf[TJ];
        int kidx = s*32 + (lane>>4)*8;
        #pragma unroll
        for (int t=0;t<TI;++t){
            int row = wm*(TI*16) + t*16 + (lane&15);
            af[t] = *(const short8*)(&Als[row*LDA + kidx]);
        }
        #pragma unroll
        for (int t=0;t<TJ;++t){
            int col = wn*(TJ*16) + t*16 + (lane&15);
            bf[t] = *(const short8*)(&Bls[col*LDA + kidx]);
        }
        #pragma unroll
        for (int i=0;i<TI;++i)
            #pragma unroll
            for (int j=0;j<TJ;++j)
                acc[i][j] = __builtin_amdgcn_mfma_f32_16x16x32_bf16(af[i], bf[j], acc[i][j], 0,0,0);
    }
}

// swapped orientation: acc row = wm*(TI*16)+i*16+cl, col = wn*(TJ*16)+j*16+quad*4+rg
template<int TI, int TJ>
__device__ __forceinline__ void mma_tile_sw(
    const unsigned short* Als, const unsigned short* Bls,
    int wm, int wn, int lane, floatx4 acc[TI][TJ])
{
    #pragma unroll
    for (int s=0; s<2; ++s){
        short8 af[TI], bf[TJ];
        int kidx = s*32 + (lane>>4)*8;
        #pragma unroll
        for (int t=0;t<TI;++t){
            int row = wm*(TI*16) + t*16 + (lane&15);
            af[t] = *(const short8*)(&Als[row*LDA + kidx]);
        }
        #pragma unroll
        for (int t=0;t<TJ;++t){
            int col = wn*(TJ*16) + t*16 + (lane&15);
            bf[t] = *(const short8*)(&Bls[col*LDA + kidx]);
        }
        #pragma unroll
        for (int i=0;i<TI;++i)
            #pragma unroll
            for (int j=0;j<TJ;++j)
                acc[i][j] = __builtin_amdgcn_mfma_f32_16x16x32_bf16(bf[j], af[i], acc[i][j], 0,0,0);
    }
}

// A from LDP-stride tile (K=128 resident), B from 64-wide chunk — normal orientation
__device__ __forceinline__ void mma_tileA_lp(
    const unsigned short* Atile, const unsigned short* Bls,
    int k0, int wm, int wn, int lane, floatx4 acc[4][4])
{
    #pragma unroll
    for (int s=0; s<2; ++s){
        short8 af[4], bf[4];
        int kloc = s*32 + (lane>>4)*8;
        #pragma unroll
        for (int t=0;t<4;++t){
            int row = wm*64 + t*16 + (lane&15);
            af[t] = *(const short8*)(&Atile[row*LDP + k0 + kloc]);
            int col = wn*64 + t*16 + (lane&15);
            bf[t] = *(const short8*)(&Bls[col*LDA + kloc]);
        }
        #pragma unroll
        for (int i=0;i<4;++i)
            #pragma unroll
            for (int j=0;j<4;++j)
                acc[i][j] = __builtin_amdgcn_mfma_f32_16x16x32_bf16(af[i], bf[j], acc[i][j], 0,0,0);
    }
}

// ---------------- K-PQ: 64x64 tiles, grid (64,12)=768 blocks, 18.4KB LDS ----------------
__global__ __launch_bounds__(256) void k_pq(
    const unsigned short* __restrict__ A, const unsigned short* __restrict__ Bw,
    unsigned short* __restrict__ PQbf,
    const float* __restrict__ bm1l, const float* __restrict__ bue1l)
{
    __shared__ __align__(16) unsigned short smem[2*64*LDA];   // 9216 shorts = 18432 B
    unsigned short* Als = smem;
    unsigned short* Bls = smem + 64*LDA;
    unsigned short* tile = smem;            // 64*LDP = 8704 shorts, reuse after GEMM
    int tid = threadIdx.x;
    int lane = tid & 63, wave = tid >> 6;
    int wm = wave >> 1, wn = wave & 1;      // wave tile 32 x 32
    const unsigned short* Ab = A + (size_t)blockIdx.x*64*256;
    const unsigned short* Bb = Bw + (size_t)blockIdx.y*64*256;
    floatx4 acc[2][2];
    #pragma unroll
    for (int i=0;i<2;++i)
        #pragma unroll
        for (int j=0;j<2;++j) acc[i][j] = (floatx4){0.f,0.f,0.f,0.f};
    for (int k0=0; k0<256; k0+=BK){
        stage_tile_t<64>(Ab, 256, k0, Als, tid);
        stage_tile_t<64>(Bb, 256, k0, Bls, tid);
        __syncthreads();
        mma_tile_sw<2,2>(Als, Bls, wm, wn, lane, acc);
        __syncthreads();
    }
    int quad = lane >> 4, cl = lane & 15;
    #pragma unroll
    for (int i=0;i<2;++i){
        int rowl = wm*32 + i*16 + cl;
        #pragma unroll
        for (int j=0;j<2;++j){
            int coll = wn*32 + j*16 + quad*4;
            int col0 = blockIdx.y*64 + coll;
            float4 bv;
            if (col0 < 256)      bv = *(const float4*)&bm1l[col0];
            else if (col0 < 384) bv = *(const float4*)&bue1l[col0-256];
            else                 bv = (float4){0.f,0.f,0.f,0.f};
            sh4 w;
            w[0] = (short)f2bf(acc[i][j][0] + bv.x);
            w[1] = (short)f2bf(acc[i][j][1] + bv.y);
            w[2] = (short)f2bf(acc[i][j][2] + bv.z);
            w[3] = (short)f2bf(acc[i][j][3] + bv.w);
            *(sh4*)(&tile[rowl*LDP + coll]) = w;
        }
    }
    __syncthreads();
    {
        int rl = tid >> 2;                  // 0..63
        int h  = tid & 3;                   // 16-col chunk
        unsigned short* dst = PQbf + (size_t)(blockIdx.x*64 + rl)*768 + blockIdx.y*64 + h*16;
        *(short8*)(dst + 0) = *(const short8*)(&tile[rl*LDP + h*16 + 0]);
        *(short8*)(dst + 8) = *(const short8*)(&tile[rl*LDP + h*16 + 8]);
    }
}

// ---------------- K4a: S path (colblks 0,1) — round-3 proven form ----------------
__global__ __launch_bounds__(256) void k_h1s(
    const unsigned short* __restrict__ Apad, const unsigned short* __restrict__ Bw,
    const unsigned short* __restrict__ PQbf, const int* __restrict__ jg_pad,
    const float* __restrict__ mask_pad,
    unsigned short* __restrict__ Sout)
{
    __shared__ __align__(16) unsigned short smem[2*128*LDA];
    __shared__ float smask[128];
    unsigned short* Als = smem;
    unsigned short* Bls = smem + 128*LDA;
    unsigned short* pqT = smem;             // transposed tile [col][row], reuse after GEMM

    int tid = threadIdx.x;
    int lane = tid & 63, wave = tid >> 6;
    int wm = wave >> 1, wn = wave & 1;
    int colblk = blockIdx.y;                // 0 or 1

    const unsigned short* Ab = Apad + (size_t)blockIdx.x*128*128;
    const unsigned short* Bb = Bw + (size_t)colblk*128*128;
    floatx4 acc[4][4];
    #pragma unroll
    for (int i=0;i<4;++i)
        #pragma unroll
        for (int j=0;j<4;++j) acc[i][j] = (floatx4){0.f,0.f,0.f,0.f};
    for (int k0=0; k0<128; k0+=BK){
        stage_tile_t<128>(Ab, 128, k0, Als, tid);
        stage_tile_t<128>(Bb, 128, k0, Bls, tid);
        __syncthreads();
        mma_tile_t<4,4>(Als, Bls, wm, wn, lane, acc);
        __syncthreads();
    }

    // ---- transposed PQ gather: work item = 4 rows x 8 cols ----
    {
        int colbase = colblk*128;
        #pragma unroll
        for (int it=0; it<2; ++it){
            int w    = it*256 + tid;
            int rq   = w & 31;              // 4-row block
            int c8   = w >> 5;              // 8-col block
            int row0 = rq*4;
            int r0   = blockIdx.x*128 + row0;
            int ni   = r0 >> 5;             // same node for all 4 rows
            int4 jg4 = *(const int4*)&jg_pad[r0];
            int colg = colbase + c8*8;
            short8 pv = *(const short8*)(PQbf + (size_t)ni*768 + colg);
            short8 q0 = *(const short8*)(PQbf + (size_t)jg4.x*768 + 384 + colg);
            short8 q1 = *(const short8*)(PQbf + (size_t)jg4.y*768 + 384 + colg);
            short8 q2 = *(const short8*)(PQbf + (size_t)jg4.z*768 + 384 + colg);
            short8 q3 = *(const short8*)(PQbf + (size_t)jg4.w*768 + 384 + colg);
            #pragma unroll
            for (int q=0; q<8; ++q){
                float pf = bf2f((unsigned short)pv[q]);
                sh4 ov;
                ov[0] = (short)f2bf(pf + bf2f((unsigned short)q0[q]));
                ov[1] = (short)f2bf(pf + bf2f((unsigned short)q1[q]));
                ov[2] = (short)f2bf(pf + bf2f((unsigned short)q2[q]));
                ov[3] = (short)f2bf(pf + bf2f((unsigned short)q3[q]));
                *(sh4*)(&pqT[(c8*8 + q)*LDP + row0]) = ov;
            }
        }
        if (tid < 128) smask[tid] = mask_pad[blockIdx.x*128 + tid];
    }
    __syncthreads();

    int quad = lane >> 4, cl = lane & 15;
    float sumA[4] = {0.f,0.f,0.f,0.f};
    float sumB[4] = {0.f,0.f,0.f,0.f};
    #pragma unroll
    for (int i=0;i<4;++i){
        int rowl0 = wm*64 + i*16 + quad*4;
        float4 mk = *(const float4*)&smask[rowl0];
        float mkv[4] = {mk.x, mk.y, mk.z, mk.w};
        #pragma unroll
        for (int j=0;j<4;++j){
            int coll = wn*64 + j*16 + cl;
            sh4 pq4 = *(const sh4*)(&pqT[coll*LDP + rowl0]);
            #pragma unroll
            for (int rg=0; rg<4; ++rg){
                float v  = softplusf(acc[i][j][rg] + bf2f((unsigned short)pq4[rg]));
                float mv = mkv[rg]*v;
                if (i < 2) sumA[j] += mv; else sumB[j] += mv;
            }
        }
    }

    // rows wm*64..wm*64+63 = nodes (bx*4 + 2wm), (bx*4 + 2wm + 1)
    int nodeA = blockIdx.x*4 + wm*2;
    #pragma unroll
    for (int j=0;j<4;++j){
        float a = sumA[j];
        a += __shfl_xor(a, 16, 64);
        a += __shfl_xor(a, 32, 64);
        float b = sumB[j];
        b += __shfl_xor(b, 16, 64);
        b += __shfl_xor(b, 32, 64);
        int col = colblk*128 + wn*64 + j*16 + cl;
        if (quad == 0)      Sout[(size_t)nodeA*256 + col]     = f2bf(a);
        else if (quad == 1) Sout[(size_t)(nodeA+1)*256 + col] = f2bf(b);
    }
}

// ---------------- K4b: edge path FUSED with edge residual update — round-3 proven form ----------------
__global__ __launch_bounds__(256) void k_h1e(
    const unsigned short* __restrict__ Apad, const unsigned short* __restrict__ BwE,
    const unsigned short* __restrict__ BwU2,
    const unsigned short* __restrict__ PQbf, const int* __restrict__ jg_pad,
    const float* __restrict__ mask_pad, const float* __restrict__ bue2l,
    unsigned short* __restrict__ edge_pad, float* __restrict__ edge_f32,
    int last)
{
    __shared__ __align__(16) unsigned short smem[26624];   // 53248 B
    unsigned short* Als  = smem;
    unsigned short* Bls  = smem + 128*LDA;      // +9216
    unsigned short* tile = smem;                // 128*LDP = 17408 shorts
    unsigned short* B2   = smem + 128*LDP;      // +17408 .. 26624

    int tid = threadIdx.x;
    int lane = tid & 63, wave = tid >> 6;
    int wm = wave >> 1, wn = wave & 1;

    const unsigned short* Ab = Apad + (size_t)blockIdx.x*128*128;
    floatx4 acc[4][4];
    #pragma unroll
    for (int i=0;i<4;++i)
        #pragma unroll
        for (int j=0;j<4;++j) acc[i][j] = (floatx4){0.f,0.f,0.f,0.f};
    for (int k0=0; k0<128; k0+=BK){
        stage_tile_t<128>(Ab, 128, k0, Als, tid);
        stage_tile_t<128>(BwE, 128, k0, Bls, tid);
        __syncthreads();
        mma_tile_t<4,4>(Als, Bls, wm, wn, lane, acc);
        __syncthreads();
    }

    // ---- early-issue GEMM2 first weight chunk ----
    stage_tile_t<128>(BwU2, 128, 0, B2, tid);

    // ---- PQ gather (row-major, cols 256..383) into tile ----
    {
        int rl = tid >> 1;
        int h  = tid & 1;
        int r  = blockIdx.x*128 + rl;
        int ni = r >> 5;
        int jg = jg_pad[r];
        int cb = 256 + h*64;
        const unsigned short* Pr = PQbf + (size_t)ni*768 + cb;
        const unsigned short* Qr = PQbf + (size_t)jg*768 + 384 + cb;
        #pragma unroll
        for (int q=0; q<8; ++q){
            short8 pv = *(const short8*)(Pr + q*8);
            short8 qv = *(const short8*)(Qr + q*8);
            short8 ov;
            #pragma unroll
            for (int z=0; z<8; ++z)
                ov[z] = (short)f2bf(bf2f((unsigned short)pv[z]) + bf2f((unsigned short)qv[z]));
            *(short8*)(&tile[rl*LDP + h*64 + q*8]) = ov;
        }
    }
    __syncthreads();

    // ---- softplus(acc + PQ) in place (sole-owner slots) ----
    int quad = lane >> 4, cl = lane & 15;
    #pragma unroll
    for (int i=0;i<4;++i){
        #pragma unroll
        for (int rg=0;rg<4;++rg){
            int rowl = wm*64 + i*16 + quad*4 + rg;
            #pragma unroll
            for (int j=0;j<4;++j){
                int coll = wn*64 + j*16 + cl;
                float pq = bf2f(tile[rowl*LDP + coll]);
                float v  = softplusf(acc[i][j][rg] + pq);
                tile[rowl*LDP + coll] = f2bf(v);
            }
        }
    }
    __syncthreads();

    // ---- GEMM2: acc2 = H1(tile) @ Wue2 ----
    floatx4 acc2[4][4];
    #pragma unroll
    for (int i=0;i<4;++i)
        #pragma unroll
        for (int j=0;j<4;++j) acc2[i][j] = (floatx4){0.f,0.f,0.f,0.f};
    mma_tileA_lp(tile, B2, 0, wm, wn, lane, acc2);
    __syncthreads();                            // B2(0) free
    stage_tile_t<128>(BwU2, 128, 64, B2, tid);
    __syncthreads();
    mma_tileA_lp(tile, B2, 64, wm, wn, lane, acc2);
    __syncthreads();                            // tile & B2 free

    // ---- write acc2 into tile; load bias into dead B2 space ----
    float* sbias = (float*)B2;
    #pragma unroll
    for (int i=0;i<4;++i){
        #pragma unroll
        for (int rg=0;rg<4;++rg){
            int rowl = wm*64 + i*16 + quad*4 + rg;
            #pragma unroll
            for (int j=0;j<4;++j){
                int coll = wn*64 + j*16 + cl;
                tile[rowl*LDP + coll] = f2bf(acc2[i][j][rg]);
            }
        }
    }
    if (tid < 128) sbias[tid] = bue2l[tid];
    __syncthreads();

    // ---- edge residual epilogue, full-line coalesced writes ----
    if (last){
        int c16  = lane & 31;
        int rsub = lane >> 5;
        #pragma unroll
        for (int step=0; step<16; ++step){
            int rowl = wave*32 + step*2 + rsub;
            int R = blockIdx.x*128 + rowl;
            int k = R & (KP-1);
            if (k < Kn){
                float mij = mask_pad[R];
                int node = R >> 5;
                int e = node*Kn + k;
                sh4 ov = *(const sh4*)(edge_pad + (size_t)R*128 + c16*4);
                sh4 av = *(const sh4*)(&tile[rowl*LDP + c16*4]);
                float4 bv = *(const float4*)(&sbias[c16*4]);
                float4 f;
                f.x = (bf2f((unsigned short)ov[0]) + bf2f((unsigned short)av[0]) + bv.x)*mij;
                f.y = (bf2f((unsigned short)ov[1]) + bf2f((unsigned short)av[1]) + bv.y)*mij;
                f.z = (bf2f((unsigned short)ov[2]) + bf2f((unsigned short)av[2]) + bv.z)*mij;
                f.w = (bf2f((unsigned short)ov[3]) + bf2f((unsigned short)av[3]) + bv.w)*mij;
                *(float4*)(edge_f32 + (size_t)e*128 + c16*4) = f;
            }
        }
    } else {
        int c8   = lane & 15;
        int rsub = lane >> 4;
        #pragma unroll
        for (int step=0; step<8; ++step){
            int rowl = wave*32 + step*4 + rsub;
            int R = blockIdx.x*128 + rowl;
            int k = R & (KP-1);
            if (k < Kn){
                float mij = mask_pad[R];
                unsigned short* ep = edge_pad + (size_t)R*128 + c8*8;
                short8 ov = *(const short8*)ep;
                short8 av = *(const short8*)(&tile[rowl*LDP + c8*8]);
                float4 b0 = *(const float4*)(&sbias[c8*8]);
                float4 b1 = *(const float4*)(&sbias[c8*8 + 4]);
                float nv[8];
                nv[0] = (bf2f((unsigned short)ov[0]) + bf2f((unsigned short)av[0]) + b0.x)*mij;
                nv[1] = (bf2f((unsigned short)ov[1]) + bf2f((unsigned short)av[1]) + b0.y)*mij;
                nv[2] = (bf2f((unsigned short)ov[2]) + bf2f((unsigned short)av[2]) + b0.z)*mij;
                nv[3] = (bf2f((unsigned short)ov[3]) + bf2f((unsigned short)av[3]) + b0.w)*mij;
                nv[4] = (bf2f((unsigned short)ov[4]) + bf2f((unsigned short)av[4]) + b1.x)*mij;
                nv[5] = (bf2f((unsigned short)ov[5]) + bf2f((unsigned short)av[5]) + b1.y)*mij;
                nv[6] = (bf2f((unsigned short)ov[6]) + bf2f((unsigned short)av[6]) + b1.z)*mij;
                nv[7] = (bf2f((unsigned short)ov[7]) + bf2f((unsigned short)av[7]) + b1.w)*mij;
                short8 sv;
                #pragma unroll
                for (int z=0; z<8; ++z) sv[z] = (short)f2bf(nv[z]);
                *(short8*)ep = sv;
            }
        }
    }
}

// ---------------- K5: node update, 32x64 tiles, grid (128,4)=512 blocks ----------------
__global__ __launch_bounds__(256) void k_node_gemm(
    const unsigned short* __restrict__ S, const unsigned short* __restrict__ Bw,
    const float* __restrict__ bm2l, const float* __restrict__ cnt,
    const float* __restrict__ mask_i,
    float* __restrict__ node_h, unsigned short* __restrict__ node_bf)
{
    __shared__ __align__(16) unsigned short Als[32*LDA];
    __shared__ __align__(16) unsigned short Bls[64*LDA];
    int tid = threadIdx.x;
    int lane = tid & 63, wave = tid >> 6;
    int wm = wave >> 1, wn = wave & 1;      // wave tile 16 x 32
    const unsigned short* Ab = S + (size_t)blockIdx.x*32*256;
    const unsigned short* Bb = Bw + (size_t)blockIdx.y*64*256;
    floatx4 acc[1][2];
    acc[0][0] = (floatx4){0.f,0.f,0.f,0.f};
    acc[0][1] = (floatx4){0.f,0.f,0.f,0.f};
    for (int k0=0; k0<256; k0+=BK){
        stage_tile_t<32>(Ab, 256, k0, Als, tid);
        stage_tile_t<64>(Bb, 256, k0, Bls, tid);
        __syncthreads();
        mma_tile_sw<1,2>(Als, Bls, wm, wn, lane, acc);
        __syncthreads();
    }
    int quad = lane >> 4, cl = lane & 15;
    {
        int nid = blockIdx.x*32 + wm*16 + cl;
        float ct = cnt[nid];
        float mi = mask_i[nid];
        float dv = ct + EPSF;
        #pragma unroll
        for (int j=0;j<2;++j){
            int col = blockIdx.y*64 + wn*32 + j*16 + quad*4;
            float4 bv = *(const float4*)&bm2l[col];
            float4 nh = *(const float4*)&node_h[(size_t)nid*256 + col];
            float4 r;
            r.x = (nh.x + (acc[0][j][0] + ct*bv.x)/dv)*mi;
            r.y = (nh.y + (acc[0][j][1] + ct*bv.y)/dv)*mi;
            r.z = (nh.z + (acc[0][j][2] + ct*bv.z)/dv)*mi;
            r.w = (nh.w + (acc[0][j][3] + ct*bv.w)/dv)*mi;
            *(float4*)&node_h[(size_t)nid*256 + col] = r;
            sh4 w;
            w[0] = (short)f2bf(r.x);
            w[1] = (short)f2bf(r.y);
            w[2] = (short)f2bf(r.z);
            w[3] = (short)f2bf(r.w);
            *(sh4*)&node_bf[(size_t)nid*256 + col] = w;
        }
    }
}

extern "C" void kernel_launch(void* const* d_in, const int* in_sizes, int n_in,
                              void* d_out, int out_size, void* d_ws, size_t ws_size,
                              hipStream_t stream)
{
    (void)in_sizes; (void)n_in; (void)out_size; (void)ws_size;
    const float* X   = (const float*)d_in[0];
    const int*   C   = (const int*)  d_in[1];
    const float* Wn  = (const float*)d_in[2];
    const float* bn  = (const float*)d_in[3];
    const float* We  = (const float*)d_in[4];
    const float* be  = (const float*)d_in[5];
    const float* Wm1 = (const float*)d_in[6];
    const float* bm1 = (const float*)d_in[7];
    const float* Wm2 = (const float*)d_in[8];
    const float* bm2 = (const float*)d_in[9];
    const float* Wue1= (const float*)d_in[10];
    const float* bue1= (const float*)d_in[11];
    const float* Wue2= (const float*)d_in[12];
    const float* bue2= (const float*)d_in[13];

    float* out       = (float*)d_out;
    float* out_node  = out;                    // (B,N,DN)    1048576
    float* out_edge  = out + 1048576;          // (B,N,K,DE) 15728640
    float* out_eidxf = out + 16777216;         // (B,N,K)      122880
    float* out_maski = out + 16900096;         // (B,N)          4096
    float* out_maskij= out + 16904192;         // (B,N,K)      122880

    char* wsb = (char*)d_ws;
    size_t off = 0;
    float* wXc    = (float*)(wsb + off); off += (size_t)12288*4;
    float* wR     = (float*)(wsb + off); off += (size_t)36864*4;
    float* wF     = (float*)(wsb + off); off += (size_t)49152*4;
    int*   wEidx  = (int*)  (wsb + off); off += (size_t)EDGES*4;
    int*   wJgPad = (int*)  (wsb + off); off += (size_t)RPAD*4;
    float* wMaskP = (float*)(wsb + off); off += (size_t)RPAD*4;
    float* wCnt   = (float*)(wsb + off); off += (size_t)NODES*4;
    unsigned short* wPQ      = (unsigned short*)(wsb + off); off += (size_t)NODES*768*2;
    unsigned short* wS       = (unsigned short*)(wsb + off); off += (size_t)NODES*256*2;
    unsigned short* wNodeBf  = (unsigned short*)(wsb + off); off += (size_t)NODES*256*2;
    unsigned short* wEdgePad = (unsigned short*)(wsb + off); off += (size_t)RPAD*128*2;
    unsigned short* wFeatP   = (unsigned short*)(wsb + off); off += (size_t)RPAD*32*2;
    unsigned short* wWe0     = (unsigned short*)(wsb + off); off += (size_t)128*32*2;
    unsigned short* wPQw     = (unsigned short*)(wsb + off); off += (size_t)3*768*256*2;
    unsigned short* wEw      = (unsigned short*)(wsb + off); off += (size_t)3*384*128*2;
    unsigned short* wUe2w    = (unsigned short*)(wsb + off); off += (size_t)3*128*128*2;
    unsigned short* wM2w     = (unsigned short*)(wsb + off); off += (size_t)3*256*256*2;

    k_geom <<<16,    256, 0, stream>>>(X, C, wXc, wR, wF, out_maski);
    k_nodeh<<<NODES, 256, 0, stream>>>(wF, Wn, bn, C, out_node, wNodeBf);
    k_knn  <<<NODES/4, 256, 0, stream>>>(wXc, C, wEidx, out_eidxf);

    k_pack_all<<<3856, 256, 0, stream>>>(We, Wm1, Wue1, Wue2, Wm2,
                                         wWe0, wPQw, wEw, wUe2w, wM2w);
    k_edge_feat<<<RPAD/256, 256, 0, stream>>>(wXc, wR, wEidx, C, wFeatP,
                                              out_maskij, wMaskP, wJgPad, wCnt);
    k_edge0<<<RPAD/128, 256, 0, stream>>>(wFeatP, wWe0, be, wMaskP, wEdgePad);

    for (int l=0; l<3; ++l){
        k_pq<<<dim3(64,12), 256, 0, stream>>>(wNodeBf, wPQw + (size_t)l*768*256, wPQ,
                                              bm1 + l*256, bue1 + l*128);
        k_h1s<<<dim3(RPAD/128,2), 256, 0, stream>>>(
            wEdgePad, wEw + (size_t)l*384*128, wPQ, wJgPad, wMaskP, wS);
        k_h1e<<<RPAD/128, 256, 0, stream>>>(
            wEdgePad, wEw + (size_t)l*384*128 + (size_t)256*128,
            wUe2w + (size_t)l*128*128, wPQ, wJgPad, wMaskP, bue2 + l*128,
            wEdgePad, out_edge, (l==2) ? 1 : 0);
        k_node_gemm<<<dim3(NODES/32,4), 256, 0, stream>>>(
            wS, wM2w + (size_t)l*256*256, bm2 + l*256, wCnt, out_maski,
            out_node, wNodeBf);
    }
}